// Round 6
// baseline (1910.827 us; speedup 1.0000x reference)
//
#include <hip/hip_runtime.h>
#include <hip/hip_bf16.h>

#define TT 32
#define DD 128
#define HH 256
#define VV 32000
#define ZZ 256
#define NTL 50            // n-slabs for V-GEMM (50 x 640 = 32000)
#define GHP 1544          // gh LDS pitch (floats): 1536 + 8 -> <=2-way conflicts

typedef __attribute__((ext_vector_type(8))) short bf16x8;
typedef __attribute__((ext_vector_type(4))) float f32x4;
typedef __attribute__((ext_vector_type(8))) _Float16 f16x8;
typedef _Float16 h2v __attribute__((ext_vector_type(2)));

static __device__ inline unsigned short f2bf(float x) {
    __hip_bfloat16 h = __float2bfloat16(x);
    return *(unsigned short*)&h;
}

// ---------------- edges canonicalizer (bool-vs-int32 layout detect) ----------------
__global__ void edge_canon_k(const unsigned char* __restrict__ eb,
                             unsigned char* __restrict__ canon)
{
    __shared__ int flag;
    if (threadIdx.x == 0) flag = 0;
    __syncthreads();
    int acc = 0;
    for (int i = threadIdx.x; i < TT * DD; i += 256)
        if (i & 3) acc |= eb[i];
    if (acc) atomicOr(&flag, 1);
    __syncthreads();
    const bool is_i32 = (flag == 0);
    for (int i = threadIdx.x; i < TT * DD; i += 256)
        canon[i] = is_i32 ? eb[4 * (size_t)i] : eb[i];
}

// ---------------- pack f32 [nrow16*16][256] -> fragment-linear bf16 ----------------
// chunk i = (j*8 + ks)*64 + lane ; lane=(g,c) holds src[j*16+c][ks*32+g*8 .. +8]
__global__ __launch_bounds__(256) void pack_frag(
    const float* __restrict__ src, __hip_bfloat16* __restrict__ dst, int nchunks_total)
{
    int i = blockIdx.x * 256 + threadIdx.x;
    if (i >= nchunks_total) return;
    int lane = i & 63, ks = (i >> 6) & 7, j = i >> 9;
    int g = lane >> 4, c = lane & 15;
    const float* s = src + (size_t)(j * 16 + c) * HH + ks * 32 + g * 8;
    float4 v0 = *(const float4*)s;
    float4 v1 = *(const float4*)(s + 4);
    bf16x8 o;
    o[0] = (short)f2bf(v0.x); o[1] = (short)f2bf(v0.y);
    o[2] = (short)f2bf(v0.z); o[3] = (short)f2bf(v0.w);
    o[4] = (short)f2bf(v1.x); o[5] = (short)f2bf(v1.y);
    o[6] = (short)f2bf(v1.z); o[7] = (short)f2bf(v1.w);
    *(bf16x8*)(dst + (size_t)i * 8) = o;
}

// ---------------- pack f32 [nrow16*16][256] -> fragment-linear f16 ----------------
__global__ __launch_bounds__(256) void pack_frag16(
    const float* __restrict__ src, _Float16* __restrict__ dst, int nchunks_total)
{
    int i = blockIdx.x * 256 + threadIdx.x;
    if (i >= nchunks_total) return;
    int lane = i & 63, ks = (i >> 6) & 7, j = i >> 9;
    int g = lane >> 4, c = lane & 15;
    const float* s = src + (size_t)(j * 16 + c) * HH + ks * 32 + g * 8;
    float4 v0 = *(const float4*)s;
    float4 v1 = *(const float4*)(s + 4);
    f16x8 o;
    o[0] = (_Float16)v0.x; o[1] = (_Float16)v0.y;
    o[2] = (_Float16)v0.z; o[3] = (_Float16)v0.w;
    o[4] = (_Float16)v1.x; o[5] = (_Float16)v1.y;
    o[6] = (_Float16)v1.z; o[7] = (_Float16)v1.w;
    *(f16x8*)(dst + (size_t)i * 8) = o;
}

// ---------------- gather emb rows by token -> packed fragment A [4096][256] ----------------
__global__ __launch_bounds__(256) void gather_pack(
    const int* __restrict__ nodes, const float* __restrict__ emb,
    __hip_bfloat16* __restrict__ dst)
{
    int i = blockIdx.x * 256 + threadIdx.x;      // 131072 chunks
    int lane = i & 63, ks = (i >> 6) & 7, j = i >> 9;
    int g = lane >> 4, c = lane & 15;
    int row = j * 16 + c;
    int tok = nodes[row];
    const float* s = emb + (size_t)tok * HH + ks * 32 + g * 8;
    float4 v0 = *(const float4*)s;
    float4 v1 = *(const float4*)(s + 4);
    bf16x8 o;
    o[0] = (short)f2bf(v0.x); o[1] = (short)f2bf(v0.y);
    o[2] = (short)f2bf(v0.z); o[3] = (short)f2bf(v0.w);
    o[4] = (short)f2bf(v1.x); o[5] = (short)f2bf(v1.y);
    o[6] = (short)f2bf(v1.z); o[7] = (short)f2bf(v1.w);
    *(bf16x8*)(dst + (size_t)i * 8) = o;
}

// ---------------- transpose 256x256 f32 (latent weights) ----------------
__global__ __launch_bounds__(256) void pack_lat_t(
    const float* __restrict__ src, float* __restrict__ dst)
{
    int i = blockIdx.x * 256 + threadIdx.x;   // 65536
    int j = i & 255, k = i >> 8;
    dst[(size_t)k * 256 + j] = src[(size_t)j * 256 + k];
}

// ============ register-stationary GEMM, packed operands ============
template<bool WRITE_C, bool HAS_BIAS, bool LSE_PARTIAL, bool LSE_SUB>
__global__ __launch_bounds__(256, 4) void gemm_rs(
    const __hip_bfloat16* __restrict__ A,
    const __hip_bfloat16* __restrict__ B,
    int ldc, int nchunks, int ntiles,
    const float* __restrict__ bias,
    const float* __restrict__ lse,
    float* __restrict__ C,
    float* __restrict__ pm, float* __restrict__ ps)
{
    __shared__ float lds_st[WRITE_C ? (4 * 16 * 68) : 1];

    const int tid  = threadIdx.x;
    const int w    = tid >> 6;
    const int lane = tid & 63;
    const int g    = lane >> 4;
    const int c    = lane & 15;
    const int m0   = blockIdx.x * 64;
    const int row16 = m0 + w * 16;
    const int n0   = blockIdx.y * (nchunks * 64);
    const int jb0  = n0 >> 4;

    bf16x8 a[8];
    {
        const __hip_bfloat16* ap = A + (((size_t)(row16 >> 4) * 8) * 64 + lane) * 8;
#pragma unroll
        for (int ks = 0; ks < 8; ++ks) a[ks] = *(const bf16x8*)(ap + ks * 512);
    }

    float mrun[4], srun[4];
#pragma unroll
    for (int r = 0; r < 4; ++r) { mrun[r] = -3.0e38f; srun[r] = 0.f; }

    float lsev[4];
    if (LSE_SUB) {
#pragma unroll
        for (int r = 0; r < 4; ++r) lsev[r] = lse[row16 + 4 * g + r];
    }

    for (int nc = 0; nc < nchunks; ++nc) {
        const int nb = n0 + nc * 64;
        const __hip_bfloat16* bp = B + (((size_t)(jb0 + nc * 4) * 8) * 64 + lane) * 8;

        f32x4 acc[4];
#pragma unroll
        for (int nf = 0; nf < 4; ++nf) acc[nf] = (f32x4){0.f, 0.f, 0.f, 0.f};

#pragma unroll
        for (int ks = 0; ks < 8; ++ks) {
            bf16x8 b0 = *(const bf16x8*)(bp + (0 * 8 + ks) * 512);
            bf16x8 b1 = *(const bf16x8*)(bp + (1 * 8 + ks) * 512);
            bf16x8 b2 = *(const bf16x8*)(bp + (2 * 8 + ks) * 512);
            bf16x8 b3 = *(const bf16x8*)(bp + (3 * 8 + ks) * 512);
            acc[0] = __builtin_amdgcn_mfma_f32_16x16x32_bf16(a[ks], b0, acc[0], 0, 0, 0);
            acc[1] = __builtin_amdgcn_mfma_f32_16x16x32_bf16(a[ks], b1, acc[1], 0, 0, 0);
            acc[2] = __builtin_amdgcn_mfma_f32_16x16x32_bf16(a[ks], b2, acc[2], 0, 0, 0);
            acc[3] = __builtin_amdgcn_mfma_f32_16x16x32_bf16(a[ks], b3, acc[3], 0, 0, 0);
        }

        float bv[4] = {0.f, 0.f, 0.f, 0.f};
        if (HAS_BIAS) {
#pragma unroll
            for (int nf = 0; nf < 4; ++nf) bv[nf] = bias[nb + nf * 16 + c];
        }

        if (LSE_PARTIAL) {
#pragma unroll
            for (int r = 0; r < 4; ++r) {
                float l0 = acc[0][r] + bv[0];
                float l1 = acc[1][r] + bv[1];
                float l2 = acc[2][r] + bv[2];
                float l3 = acc[3][r] + bv[3];
                float mc = fmaxf(fmaxf(l0, l1), fmaxf(l2, l3));
                float mn = fmaxf(mrun[r], mc);
                srun[r] = srun[r] * __expf(mrun[r] - mn)
                        + __expf(l0 - mn) + __expf(l1 - mn)
                        + __expf(l2 - mn) + __expf(l3 - mn);
                mrun[r] = mn;
            }
        }

        if (WRITE_C) {
            const int base = w * (16 * 68);
#pragma unroll
            for (int nf = 0; nf < 4; ++nf)
#pragma unroll
                for (int r = 0; r < 4; ++r) {
                    float v = acc[nf][r] + bv[nf];
                    if (LSE_SUB) v -= lsev[r];
                    lds_st[base + (4 * g + r) * 68 + nf * 16 + c] = v;
                }
#pragma unroll
            for (int i = 0; i < 4; ++i) {
                int lr = i * 4 + g;
                float4 v = *(const float4*)&lds_st[base + lr * 68 + c * 4];
                *(float4*)(C + (size_t)(row16 + lr) * ldc + nb + c * 4) = v;
            }
        }
    }

    if (LSE_PARTIAL) {
#pragma unroll
        for (int r = 0; r < 4; ++r) {
            float m = mrun[r], s = srun[r];
#pragma unroll
            for (int mk = 1; mk <= 8; mk <<= 1) {
                float m2 = __shfl_xor(m, mk);
                float s2 = __shfl_xor(s, mk);
                float mn = fmaxf(m, m2);
                s = s * __expf(m - mn) + s2 * __expf(m2 - mn);
                m = mn;
            }
            if (c == 0) {
                int row = row16 + 4 * g + r;
                pm[(size_t)row * ntiles + blockIdx.y] = m;
                ps[(size_t)row * ntiles + blockIdx.y] = s;
            }
        }
    }
}

// ============ fused recurrence v2: MFMA d-batched, register-resident weights ============
// 8 blocks x 16 d-rows x 1024 threads (16 waves). Per phase, each wave holds its
// 6 n-tiles x 8 k-slices of BOTH-variant Whh (f16 fragment-linear) in 192 VGPRs.
// Per step: 48 MFMAs/wave -> gh in LDS -> 1024-thread gate phase (wave per d-row).
__global__ __launch_bounds__(1024) void rnn_fused2(
    const unsigned char* __restrict__ ecan,
    const float* __restrict__ gi,          // [4096][3072] input-side gates
    const _Float16* __restrict__ Wf,       // [2][1536*256] fragment-linear f16
    const float* __restrict__ ecbih, const float* __restrict__ ecbhh,
    const float* __restrict__ esbih, const float* __restrict__ esbhh,
    const float* __restrict__ dcbih, const float* __restrict__ dcbhh,
    const float* __restrict__ dsbih, const float* __restrict__ dsbhh,
    const float* __restrict__ WmT, const float* __restrict__ WlT,
    const float* __restrict__ WhT,
    const float* __restrict__ b_mean, const float* __restrict__ b_logv,
    const float* __restrict__ b_l2h,
    const float* __restrict__ enc_init, const float* __restrict__ eps,
    float* __restrict__ out_mean, float* __restrict__ out_logv,
    float* __restrict__ out_z,
    __hip_bfloat16* __restrict__ outs_pk)
{
    __shared__ float    gh[16 * GHP];       // 98.8KB: gh / mean/logv/z scratch
    __shared__ _Float16 hpk[8 * 64 * 8];    // 8KB: h in A-fragment layout
    __shared__ float    hof[16 * HH];       // 16KB: h in f32

    const int tid  = threadIdx.x;
    const int w    = tid >> 6;
    const int lane = tid & 63;
    const int d0   = blockIdx.x * 16;

    // ---- init h = enc_init ----
    {
        const int d = tid >> 6, j0 = (tid & 63) * 4;
        f32x4 hv = *(const f32x4*)(enc_init + (size_t)(d0 + d) * HH + j0);
        *(f32x4*)(hof + d * HH + j0) = hv;
        h2v p0; p0[0] = (_Float16)hv[0]; p0[1] = (_Float16)hv[1];
        h2v p1; p1[0] = (_Float16)hv[2]; p1[1] = (_Float16)hv[3];
        uint2 u;
        u.x = __builtin_bit_cast(unsigned int, p0);
        u.y = __builtin_bit_cast(unsigned int, p1);
        int chunk = (j0 >> 5) * 64 + ((j0 >> 3) & 3) * 16 + d;
        *(uint2*)((char*)hpk + chunk * 16 + (j0 & 7) * 2) = u;
    }
    __syncthreads();

    for (int p = 0; p < 2; ++p) {
        // load this wave's both-variant weight fragments (once per phase)
        f16x8 bfrag[6][8];
        {
            const _Float16* wb = Wf + (size_t)p * (1536 * 256);
#pragma unroll
            for (int i = 0; i < 6; ++i) {
                const int jt = w * 6 + i;
#pragma unroll
                for (int ks = 0; ks < 8; ++ks)
                    bfrag[i][ks] = *(const f16x8*)(wb + ((size_t)(jt * 8 + ks) * 64 + lane) * 8);
            }
        }
        const float* bihc = p ? dcbih : ecbih;
        const float* bhhc = p ? dcbhh : ecbhh;
        const float* bihs = p ? dsbih : esbih;
        const float* bhhs = p ? dsbhh : esbhh;

        for (int st = 0; st < TT; ++st) {
            // ---- MFMA phase: gh[16][1536] = h[16][256] @ [Wc;Ws]^T ----
            f16x8 af[8];
#pragma unroll
            for (int ks = 0; ks < 8; ++ks)
                af[ks] = *(const f16x8*)&hpk[(ks * 64 + lane) * 8];
#pragma unroll
            for (int i = 0; i < 6; ++i) {
                f32x4 acc = (f32x4){0.f, 0.f, 0.f, 0.f};
#pragma unroll
                for (int ks = 0; ks < 8; ++ks)
                    acc = __builtin_amdgcn_mfma_f32_16x16x32_f16(af[ks], bfrag[i][ks], acc, 0, 0, 0);
                const int jt = w * 6 + i;
                const int col = jt * 16 + (lane & 15);
                const int rb  = (lane >> 4) * 4;
#pragma unroll
                for (int r = 0; r < 4; ++r)
                    gh[(rb + r) * GHP + col] = acc[r];
            }
            __syncthreads();

            // ---- gate phase: one wave per d-row ----
            {
                const int d  = tid >> 6;
                const int j0 = (tid & 63) * 4;
                const int dg = d0 + d;
                const bool e = ecan[st * DD + dg] != 0;
                const int vb = e ? 0 : 768;
                const float* gr = gi + (size_t)(st * DD + dg) * 3072 + p * 1536 + vb;
                const float* ghd = gh + d * GHP + vb;
                const float* bih = e ? bihc : bihs;
                const float* bhh = e ? bhhc : bhhs;

                f32x4 gr_r = *(const f32x4*)(gr + j0);
                f32x4 gr_z = *(const f32x4*)(gr + HH + j0);
                f32x4 gr_n = *(const f32x4*)(gr + 2 * HH + j0);
                f32x4 gh_r = *(const f32x4*)(ghd + j0);
                f32x4 gh_z = *(const f32x4*)(ghd + HH + j0);
                f32x4 gh_n = *(const f32x4*)(ghd + 2 * HH + j0);
                f32x4 bi_r = *(const f32x4*)(bih + j0);
                f32x4 bi_z = *(const f32x4*)(bih + HH + j0);
                f32x4 bi_n = *(const f32x4*)(bih + 2 * HH + j0);
                f32x4 bh_r = *(const f32x4*)(bhh + j0);
                f32x4 bh_z = *(const f32x4*)(bhh + HH + j0);
                f32x4 bh_n = *(const f32x4*)(bhh + 2 * HH + j0);
                f32x4 ho   = *(const f32x4*)(hof + d * HH + j0);

                f32x4 hn_;
#pragma unroll
                for (int m = 0; m < 4; ++m) {
                    float rg = 1.f / (1.f + __expf(-(gr_r[m] + bi_r[m] + gh_r[m] + bh_r[m])));
                    float zg = 1.f / (1.f + __expf(-(gr_z[m] + bi_z[m] + gh_z[m] + bh_z[m])));
                    float nn = tanhf(gr_n[m] + bi_n[m] + rg * (gh_n[m] + bh_n[m]));
                    hn_[m] = (1.f - zg) * nn + zg * ho[m];
                }
                *(f32x4*)(hof + d * HH + j0) = hn_;

                h2v p0; p0[0] = (_Float16)hn_[0]; p0[1] = (_Float16)hn_[1];
                h2v p1; p1[0] = (_Float16)hn_[2]; p1[1] = (_Float16)hn_[3];
                uint2 u;
                u.x = __builtin_bit_cast(unsigned int, p0);
                u.y = __builtin_bit_cast(unsigned int, p1);
                int chunk = (j0 >> 5) * 64 + ((j0 >> 3) & 3) * 16 + d;
                *(uint2*)((char*)hpk + chunk * 16 + (j0 & 7) * 2) = u;

                if (p) {
                    ushort4 ub;
                    ub.x = f2bf(hn_[0]); ub.y = f2bf(hn_[1]);
                    ub.z = f2bf(hn_[2]); ub.w = f2bf(hn_[3]);
                    size_t ch = ((size_t)(st * 8 + blockIdx.x) * 8 + (j0 >> 5)) * 64
                              + ((j0 >> 3) & 3) * 16 + d;
                    *(ushort4*)((unsigned short*)outs_pk + ch * 8 + (j0 & 7)) = ub;
                }
            }
            __syncthreads();
        }

        if (p == 0) {
            // ---- latent: mean/logv -> z -> h0, all row-local per d ----
            const int d  = tid >> 6;
            const int q  = tid & 63;          // 4-wide column group
            const int dg = d0 + d;
            {
                f32x4 sm = (f32x4){0.f, 0.f, 0.f, 0.f};
                f32x4 sl = (f32x4){0.f, 0.f, 0.f, 0.f};
                const f32x4* wm4 = (const f32x4*)WmT;
                const f32x4* wl4 = (const f32x4*)WlT;
#pragma unroll 4
                for (int k = 0; k < HH; ++k) {
                    float hv = hof[d * HH + k];
                    sm += hv * wm4[k * 64 + q];
                    sl += hv * wl4[k * 64 + q];
                }
                f32x4 mean = sm + ((const f32x4*)b_mean)[q];
                f32x4 logv = sl + ((const f32x4*)b_logv)[q];
                ((f32x4*)(out_mean + (size_t)dg * ZZ))[q] = mean;
                ((f32x4*)(out_logv + (size_t)dg * ZZ))[q] = logv;
                *(f32x4*)(gh + d * GHP + q * 4)       = mean;
                *(f32x4*)(gh + d * GHP + 256 + q * 4) = logv;
            }
            __syncthreads();
            {
                f32x4 mean = *(const f32x4*)(gh + d * GHP + q * 4);
                f32x4 logv = *(const f32x4*)(gh + d * GHP + 256 + q * 4);
                f32x4 ep   = ((const f32x4*)(eps + (size_t)dg * ZZ))[q];
                f32x4 zv;
#pragma unroll
                for (int m = 0; m < 4; ++m)
                    zv[m] = ep[m] * __expf(0.5f * logv[m]) + mean[m];
                ((f32x4*)(out_z + (size_t)dg * ZZ))[q] = zv;
                *(f32x4*)(gh + d * GHP + 512 + q * 4) = zv;
            }
            __syncthreads();
            {
                f32x4 s = (f32x4){0.f, 0.f, 0.f, 0.f};
                const f32x4* wh4 = (const f32x4*)WhT;
#pragma unroll 4
                for (int k = 0; k < ZZ; ++k) {
                    float zv = gh[d * GHP + 512 + k];
                    s += zv * wh4[k * 64 + q];
                }
                f32x4 h0v = s + ((const f32x4*)b_l2h)[q];
                const int j0 = q * 4;
                *(f32x4*)(hof + d * HH + j0) = h0v;
                h2v p0; p0[0] = (_Float16)h0v[0]; p0[1] = (_Float16)h0v[1];
                h2v p1; p1[0] = (_Float16)h0v[2]; p1[1] = (_Float16)h0v[3];
                uint2 u;
                u.x = __builtin_bit_cast(unsigned int, p0);
                u.y = __builtin_bit_cast(unsigned int, p1);
                int chunk = (j0 >> 5) * 64 + ((j0 >> 3) & 3) * 16 + d;
                *(uint2*)((char*)hpk + chunk * 16 + (j0 & 7) * 2) = u;
            }
            __syncthreads();
        }
    }
}

// ---------------- per-row logsumexp merge (one wave per row, nt <= 64) ----------------
__global__ __launch_bounds__(64) void lse_reduce(
    const float* __restrict__ pm, const float* __restrict__ ps,
    float* __restrict__ lse, int nt)
{
    int row = blockIdx.x;
    int l = threadIdx.x;
    float m = (l < nt) ? pm[(size_t)row * nt + l] : -3.0e38f;
    float s = (l < nt) ? ps[(size_t)row * nt + l] : 0.f;
    for (int mk = 1; mk <= 32; mk <<= 1) {
        float m2 = __shfl_xor(m, mk);
        float s2 = __shfl_xor(s, mk);
        float mn = fmaxf(m, m2);
        s = s * __expf(m - mn) + s2 * __expf(m2 - mn);
        m = mn;
    }
    if (l == 0) lse[row] = m + logf(s);
}

extern "C" void kernel_launch(void* const* d_in, const int* in_sizes, int n_in,
                              void* d_out, int out_size, void* d_ws, size_t ws_size,
                              hipStream_t stream)
{
    const int*           nodes     = (const int*)d_in[0];
    const unsigned char* edges_raw = (const unsigned char*)d_in[1];
    const float* emb    = (const float*)d_in[2];
    const float* ecWih  = (const float*)d_in[3];
    const float* ecWhh  = (const float*)d_in[4];
    const float* ecbih  = (const float*)d_in[5];
    const float* ecbhh  = (const float*)d_in[6];
    const float* esWih  = (const float*)d_in[7];
    const float* esWhh  = (const float*)d_in[8];
    const float* esbih  = (const float*)d_in[9];
    const float* esbhh  = (const float*)d_in[10];
    const float* dcWih  = (const float*)d_in[11];
    const float* dcWhh  = (const float*)d_in[12];
    const float* dcbih  = (const float*)d_in[13];
    const float* dcbhh  = (const float*)d_in[14];
    const float* dsWih  = (const float*)d_in[15];
    const float* dsWhh  = (const float*)d_in[16];
    const float* dsbih  = (const float*)d_in[17];
    const float* dsbhh  = (const float*)d_in[18];
    const float* W_mean = (const float*)d_in[19];
    const float* b_mean = (const float*)d_in[20];
    const float* W_logv = (const float*)d_in[21];
    const float* b_logv = (const float*)d_in[22];
    const float* W_l2h  = (const float*)d_in[23];
    const float* b_l2h  = (const float*)d_in[24];
    const float* W_out  = (const float*)d_in[25];
    const float* b_out  = (const float*)d_in[26];
    const float* enc_init = (const float*)d_in[27];
    const float* eps    = (const float*)d_in[28];

    float* out      = (float*)d_out;
    float* out_mean = out + (size_t)TT * DD * VV;
    float* out_logv = out_mean + DD * ZZ;
    float* out_z    = out_logv + DD * ZZ;
    float* gi       = out;                  // scratch in logits region: [4096][3072]

    char* ws = (char*)d_ws;
    __hip_bfloat16* outs_pk = (__hip_bfloat16*)(ws + 0);         // 2MB packed
    __hip_bfloat16* Ap      = (__hip_bfloat16*)(ws + 2097152);   // 2MB packed
    __hip_bfloat16* Wp      = (__hip_bfloat16*)(ws + 4194304);   // 16.4MB packed W_out
    __hip_bfloat16* Bp_all  = (__hip_bfloat16*)(ws + 20971520);  // 1.5MB packed Wih x4
    _Float16*       Wf      = (_Float16*)(ws + 22544384);        // 1.5MB f16 frag Whh x4
    float*          WmT     = (float*)(ws + 24117248);           // 256KB
    float*          WlT     = (float*)(ws + 24379392);           // 256KB
    float*          WhT     = (float*)(ws + 24641536);           // 256KB
    float*          pm      = (float*)(ws + 24903680);           // 800KB
    float*          ps      = (float*)(ws + 25722880);           // 800KB
    float*          lse     = (float*)(ws + 26542080);           // 16KB
    unsigned char*  ecan    = (unsigned char*)(ws + 26558464);   // 4KB

    edge_canon_k<<<1, 256, 0, stream>>>(edges_raw, ecan);
    pack_frag<<<4000, 256, 0, stream>>>(W_out, Wp, 2000 * 8 * 64);
    pack_frag<<<96, 256, 0, stream>>>(ecWih, Bp_all + 0 * (size_t)48 * 4096, 48 * 8 * 64);
    pack_frag<<<96, 256, 0, stream>>>(esWih, Bp_all + 1 * (size_t)48 * 4096, 48 * 8 * 64);
    pack_frag<<<96, 256, 0, stream>>>(dcWih, Bp_all + 2 * (size_t)48 * 4096, 48 * 8 * 64);
    pack_frag<<<96, 256, 0, stream>>>(dsWih, Bp_all + 3 * (size_t)48 * 4096, 48 * 8 * 64);
    // Whh fragment-linear f16: per phase [child(768 rows); sibling(768 rows)]
    pack_frag16<<<96, 256, 0, stream>>>(ecWhh, Wf + 0 * (size_t)768 * 256, 48 * 8 * 64);
    pack_frag16<<<96, 256, 0, stream>>>(esWhh, Wf + 1 * (size_t)768 * 256, 48 * 8 * 64);
    pack_frag16<<<96, 256, 0, stream>>>(dcWhh, Wf + 2 * (size_t)768 * 256, 48 * 8 * 64);
    pack_frag16<<<96, 256, 0, stream>>>(dsWhh, Wf + 3 * (size_t)768 * 256, 48 * 8 * 64);
    pack_lat_t<<<256, 256, 0, stream>>>(W_mean, WmT);
    pack_lat_t<<<256, 256, 0, stream>>>(W_logv, WlT);
    pack_lat_t<<<256, 256, 0, stream>>>(W_l2h, WhT);
    gather_pack<<<512, 256, 0, stream>>>(nodes, emb, Ap);

    // gi[4096][3072] = emb-gather x [all 4 W_ih]^T  (into d_out scratch)
    gemm_rs<true, false, false, false><<<dim3(64, 6), 256, 0, stream>>>(
        Ap, Bp_all, 3072, 8, 6, nullptr, nullptr, gi, nullptr, nullptr);

    // fused recurrence: encoder -> latent -> h0 -> decoder (writes packed outs)
    rnn_fused2<<<8, 1024, 0, stream>>>(
        ecan, gi, Wf,
        ecbih, ecbhh, esbih, esbhh, dcbih, dcbhh, dsbih, dsbhh,
        WmT, WlT, WhT, b_mean, b_logv, b_l2h,
        enc_init, eps, out_mean, out_logv, out_z, outs_pk);

    // pass A: LSE partials only (no C write)
    gemm_rs<false, true, true, false><<<dim3(64, NTL), 256, 0, stream>>>(
        outs_pk, Wp, VV, 10, NTL, b_out, nullptr, nullptr, pm, ps);
    lse_reduce<<<4096, 64, 0, stream>>>(pm, ps, lse, NTL);
    // pass B: recompute, write logp = logits - lse
    gemm_rs<true, true, false, true><<<dim3(64, NTL), 256, 0, stream>>>(
        outs_pk, Wp, VV, 10, NTL, b_out, lse, out, nullptr, nullptr);
}

// Round 7
// 1227.792 us; speedup vs baseline: 1.5563x; 1.5563x over previous
//
#include <hip/hip_runtime.h>
#include <hip/hip_bf16.h>

#define TT 32
#define DD 128
#define HH 256
#define VV 32000
#define ZZ 256
#define NTL 50            // n-slabs for V-GEMM (50 x 640 = 32000)
#define GHP2 776          // gh LDS pitch (floats)

typedef __attribute__((ext_vector_type(8))) short bf16x8;
typedef __attribute__((ext_vector_type(4))) float f32x4;
typedef __attribute__((ext_vector_type(8))) _Float16 f16x8;
typedef _Float16 h2v __attribute__((ext_vector_type(2)));

static __device__ inline unsigned short f2bf(float x) {
    __hip_bfloat16 h = __float2bfloat16(x);
    return *(unsigned short*)&h;
}

// ---------------- edges canonicalizer (bool-vs-int32 layout detect) ----------------
__global__ void edge_canon_k(const unsigned char* __restrict__ eb,
                             unsigned char* __restrict__ canon)
{
    __shared__ int flag;
    if (threadIdx.x == 0) flag = 0;
    __syncthreads();
    int acc = 0;
    for (int i = threadIdx.x; i < TT * DD; i += 256)
        if (i & 3) acc |= eb[i];
    if (acc) atomicOr(&flag, 1);
    __syncthreads();
    const bool is_i32 = (flag == 0);
    for (int i = threadIdx.x; i < TT * DD; i += 256)
        canon[i] = is_i32 ? eb[4 * (size_t)i] : eb[i];
}

// ---------------- pack f32 [nrow16*16][256] -> fragment-linear bf16 ----------------
__global__ __launch_bounds__(256) void pack_frag(
    const float* __restrict__ src, __hip_bfloat16* __restrict__ dst, int nchunks_total)
{
    int i = blockIdx.x * 256 + threadIdx.x;
    if (i >= nchunks_total) return;
    int lane = i & 63, ks = (i >> 6) & 7, j = i >> 9;
    int g = lane >> 4, c = lane & 15;
    const float* s = src + (size_t)(j * 16 + c) * HH + ks * 32 + g * 8;
    float4 v0 = *(const float4*)s;
    float4 v1 = *(const float4*)(s + 4);
    bf16x8 o;
    o[0] = (short)f2bf(v0.x); o[1] = (short)f2bf(v0.y);
    o[2] = (short)f2bf(v0.z); o[3] = (short)f2bf(v0.w);
    o[4] = (short)f2bf(v1.x); o[5] = (short)f2bf(v1.y);
    o[6] = (short)f2bf(v1.z); o[7] = (short)f2bf(v1.w);
    *(bf16x8*)(dst + (size_t)i * 8) = o;
}

// ---------------- pack f32 [nrow16*16][256] -> fragment-linear f16 ----------------
__global__ __launch_bounds__(256) void pack_frag16(
    const float* __restrict__ src, _Float16* __restrict__ dst, int nchunks_total)
{
    int i = blockIdx.x * 256 + threadIdx.x;
    if (i >= nchunks_total) return;
    int lane = i & 63, ks = (i >> 6) & 7, j = i >> 9;
    int g = lane >> 4, c = lane & 15;
    const float* s = src + (size_t)(j * 16 + c) * HH + ks * 32 + g * 8;
    float4 v0 = *(const float4*)s;
    float4 v1 = *(const float4*)(s + 4);
    f16x8 o;
    o[0] = (_Float16)v0.x; o[1] = (_Float16)v0.y;
    o[2] = (_Float16)v0.z; o[3] = (_Float16)v0.w;
    o[4] = (_Float16)v1.x; o[5] = (_Float16)v1.y;
    o[6] = (_Float16)v1.z; o[7] = (_Float16)v1.w;
    *(f16x8*)(dst + (size_t)i * 8) = o;
}

// ---------------- gather emb rows by token -> packed fragment A [4096][256] ----------------
__global__ __launch_bounds__(256) void gather_pack(
    const int* __restrict__ nodes, const float* __restrict__ emb,
    __hip_bfloat16* __restrict__ dst)
{
    int i = blockIdx.x * 256 + threadIdx.x;      // 131072 chunks
    int lane = i & 63, ks = (i >> 6) & 7, j = i >> 9;
    int g = lane >> 4, c = lane & 15;
    int row = j * 16 + c;
    int tok = nodes[row];
    const float* s = emb + (size_t)tok * HH + ks * 32 + g * 8;
    float4 v0 = *(const float4*)s;
    float4 v1 = *(const float4*)(s + 4);
    bf16x8 o;
    o[0] = (short)f2bf(v0.x); o[1] = (short)f2bf(v0.y);
    o[2] = (short)f2bf(v0.z); o[3] = (short)f2bf(v0.w);
    o[4] = (short)f2bf(v1.x); o[5] = (short)f2bf(v1.y);
    o[6] = (short)f2bf(v1.z); o[7] = (short)f2bf(v1.w);
    *(bf16x8*)(dst + (size_t)i * 8) = o;
}

// ---------------- transpose 256x256 f32 (latent weights) ----------------
__global__ __launch_bounds__(256) void pack_lat_t(
    const float* __restrict__ src, float* __restrict__ dst)
{
    int i = blockIdx.x * 256 + threadIdx.x;   // 65536
    int j = i & 255, k = i >> 8;
    dst[(size_t)k * 256 + j] = src[(size_t)j * 256 + k];
}

// ============ register-stationary GEMM, packed operands ============
template<bool WRITE_C, bool HAS_BIAS, bool LSE_PARTIAL, bool LSE_SUB>
__global__ __launch_bounds__(256, 4) void gemm_rs(
    const __hip_bfloat16* __restrict__ A,
    const __hip_bfloat16* __restrict__ B,
    int ldc, int nchunks, int ntiles,
    const float* __restrict__ bias,
    const float* __restrict__ lse,
    float* __restrict__ C,
    float* __restrict__ pm, float* __restrict__ ps)
{
    __shared__ float lds_st[WRITE_C ? (4 * 16 * 68) : 1];

    const int tid  = threadIdx.x;
    const int w    = tid >> 6;
    const int lane = tid & 63;
    const int g    = lane >> 4;
    const int c    = lane & 15;
    const int m0   = blockIdx.x * 64;
    const int row16 = m0 + w * 16;
    const int n0   = blockIdx.y * (nchunks * 64);
    const int jb0  = n0 >> 4;

    bf16x8 a[8];
    {
        const __hip_bfloat16* ap = A + (((size_t)(row16 >> 4) * 8) * 64 + lane) * 8;
#pragma unroll
        for (int ks = 0; ks < 8; ++ks) a[ks] = *(const bf16x8*)(ap + ks * 512);
    }

    float mrun[4], srun[4];
#pragma unroll
    for (int r = 0; r < 4; ++r) { mrun[r] = -3.0e38f; srun[r] = 0.f; }

    float lsev[4];
    if (LSE_SUB) {
#pragma unroll
        for (int r = 0; r < 4; ++r) lsev[r] = lse[row16 + 4 * g + r];
    }

    for (int nc = 0; nc < nchunks; ++nc) {
        const int nb = n0 + nc * 64;
        const __hip_bfloat16* bp = B + (((size_t)(jb0 + nc * 4) * 8) * 64 + lane) * 8;

        f32x4 acc[4];
#pragma unroll
        for (int nf = 0; nf < 4; ++nf) acc[nf] = (f32x4){0.f, 0.f, 0.f, 0.f};

#pragma unroll
        for (int ks = 0; ks < 8; ++ks) {
            bf16x8 b0 = *(const bf16x8*)(bp + (0 * 8 + ks) * 512);
            bf16x8 b1 = *(const bf16x8*)(bp + (1 * 8 + ks) * 512);
            bf16x8 b2 = *(const bf16x8*)(bp + (2 * 8 + ks) * 512);
            bf16x8 b3 = *(const bf16x8*)(bp + (3 * 8 + ks) * 512);
            acc[0] = __builtin_amdgcn_mfma_f32_16x16x32_bf16(a[ks], b0, acc[0], 0, 0, 0);
            acc[1] = __builtin_amdgcn_mfma_f32_16x16x32_bf16(a[ks], b1, acc[1], 0, 0, 0);
            acc[2] = __builtin_amdgcn_mfma_f32_16x16x32_bf16(a[ks], b2, acc[2], 0, 0, 0);
            acc[3] = __builtin_amdgcn_mfma_f32_16x16x32_bf16(a[ks], b3, acc[3], 0, 0, 0);
        }

        float bv[4] = {0.f, 0.f, 0.f, 0.f};
        if (HAS_BIAS) {
#pragma unroll
            for (int nf = 0; nf < 4; ++nf) bv[nf] = bias[nb + nf * 16 + c];
        }

        if (LSE_PARTIAL) {
#pragma unroll
            for (int r = 0; r < 4; ++r) {
                float l0 = acc[0][r] + bv[0];
                float l1 = acc[1][r] + bv[1];
                float l2 = acc[2][r] + bv[2];
                float l3 = acc[3][r] + bv[3];
                float mc = fmaxf(fmaxf(l0, l1), fmaxf(l2, l3));
                float mn = fmaxf(mrun[r], mc);
                srun[r] = srun[r] * __expf(mrun[r] - mn)
                        + __expf(l0 - mn) + __expf(l1 - mn)
                        + __expf(l2 - mn) + __expf(l3 - mn);
                mrun[r] = mn;
            }
        }

        if (WRITE_C) {
            const int base = w * (16 * 68);
#pragma unroll
            for (int nf = 0; nf < 4; ++nf)
#pragma unroll
                for (int r = 0; r < 4; ++r) {
                    float v = acc[nf][r] + bv[nf];
                    if (LSE_SUB) v -= lsev[r];
                    lds_st[base + (4 * g + r) * 68 + nf * 16 + c] = v;
                }
#pragma unroll
            for (int i = 0; i < 4; ++i) {
                int lr = i * 4 + g;
                float4 v = *(const float4*)&lds_st[base + lr * 68 + c * 4];
                *(float4*)(C + (size_t)(row16 + lr) * ldc + nb + c * 4) = v;
            }
        }
    }

    if (LSE_PARTIAL) {
#pragma unroll
        for (int r = 0; r < 4; ++r) {
            float m = mrun[r], s = srun[r];
#pragma unroll
            for (int mk = 1; mk <= 8; mk <<= 1) {
                float m2 = __shfl_xor(m, mk);
                float s2 = __shfl_xor(s, mk);
                float mn = fmaxf(m, m2);
                s = s * __expf(m - mn) + s2 * __expf(m2 - mn);
                m = mn;
            }
            if (c == 0) {
                int row = row16 + 4 * g + r;
                pm[(size_t)row * ntiles + blockIdx.y] = m;
                ps[(size_t)row * ntiles + blockIdx.y] = s;
            }
        }
    }
}

// ============ fused recurrence v3: variant-split pair blocks ============
// Grid 16 = 8 d-groups x 2 variants. Block (g,v): 512 threads (8 waves), holds
// ONLY variant-v Whh in registers (8 waves x 6 n-tiles x 8 ks = 192 VGPR/wave,
// no spill at launch_bounds(512,1)). Gates rows where edge-select==v; pair
// exchanges updated h rows via device-coherent buffer + flag handshake.
__global__ __launch_bounds__(512, 1) void rnn_fused3(
    const unsigned char* __restrict__ ecan,
    const float* __restrict__ gi,          // [4096][3072]
    const _Float16* __restrict__ Wf,       // [(p*2+v)][768*256] fragment-linear f16
    const float* __restrict__ ecbih, const float* __restrict__ ecbhh,
    const float* __restrict__ esbih, const float* __restrict__ esbhh,
    const float* __restrict__ dcbih, const float* __restrict__ dcbhh,
    const float* __restrict__ dsbih, const float* __restrict__ dsbhh,
    const float* __restrict__ WmT, const float* __restrict__ WlT,
    const float* __restrict__ WhT,
    const float* __restrict__ b_mean, const float* __restrict__ b_logv,
    const float* __restrict__ b_l2h,
    const float* __restrict__ enc_init, const float* __restrict__ eps,
    float* __restrict__ out_mean, float* __restrict__ out_logv,
    float* __restrict__ out_z,
    __hip_bfloat16* __restrict__ outs_pk,
    float* __restrict__ xh,                // [2][8][16][256] exchange
    int* __restrict__ flags)               // [64][8][2]
{
    const int g  = blockIdx.x >> 1;
    const int v  = blockIdx.x & 1;         // 0: child (e!=0), 1: sibling
    const int d0 = g * 16;
    const int tid  = threadIdx.x;
    const int w    = tid >> 6;
    const int lane = tid & 63;

    __shared__ float    gh[16 * GHP2];     // 49.7KB
    __shared__ float    hof[16 * HH];      // 16KB
    __shared__ _Float16 hpk[8 * 64 * 8];   // 8KB

    const int d  = tid >> 5;               // 0..15
    const int jq = tid & 31;               // 0..31
    const int j0 = jq * 8;
    const int dg = d0 + d;
    const int hchunk = (j0 >> 5) * 64 + ((j0 >> 3) & 3) * 16 + d;

    // ---- init h = enc_init ----
    {
        f32x4 h0v = *(const f32x4*)(enc_init + (size_t)dg * HH + j0);
        f32x4 h1v = *(const f32x4*)(enc_init + (size_t)dg * HH + j0 + 4);
        *(f32x4*)(hof + d * HH + j0)     = h0v;
        *(f32x4*)(hof + d * HH + j0 + 4) = h1v;
        f16x8 pk;
#pragma unroll
        for (int m = 0; m < 4; ++m) { pk[m] = (_Float16)h0v[m]; pk[4 + m] = (_Float16)h1v[m]; }
        *(f16x8*)&hpk[hchunk * 8] = pk;
    }
    __syncthreads();

    int gs = 0;
    for (int p = 0; p < 2; ++p) {
        // weight fragments: once per phase, variant v only
        f16x8 bfrag[6][8];
        {
            const _Float16* wb = Wf + (size_t)(p * 2 + v) * (768 * 256);
#pragma unroll
            for (int i = 0; i < 6; ++i) {
                const int jt = w * 6 + i;
#pragma unroll
                for (int ks = 0; ks < 8; ++ks)
                    bfrag[i][ks] = *(const f16x8*)(wb + ((size_t)(jt * 8 + ks) * 64 + lane) * 8);
            }
        }
        const float* bih = p ? (v ? dsbih : dcbih) : (v ? esbih : ecbih);
        const float* bhh = p ? (v ? dsbhh : dcbhh) : (v ? esbhh : ecbhh);

        for (int st = 0; st < TT; ++st) {
            // ---- MFMA: gh[16][768] = h[16][256] @ Wv^T ----
            f16x8 af[8];
#pragma unroll
            for (int ks = 0; ks < 8; ++ks)
                af[ks] = *(const f16x8*)&hpk[(ks * 64 + lane) * 8];
#pragma unroll
            for (int i = 0; i < 6; ++i) {
                f32x4 acc = (f32x4){0.f, 0.f, 0.f, 0.f};
#pragma unroll
                for (int ks = 0; ks < 8; ++ks)
                    acc = __builtin_amdgcn_mfma_f32_16x16x32_f16(af[ks], bfrag[i][ks], acc, 0, 0, 0);
                const int col = (w * 6 + i) * 16 + (lane & 15);
                const int rb  = (lane >> 4) * 4;
#pragma unroll
                for (int r = 0; r < 4; ++r)
                    gh[(rb + r) * GHP2 + col] = acc[r];
            }
            __syncthreads();

            // ---- gate selected rows ----
            const bool e   = ecan[st * DD + dg] != 0;
            const bool sel = (e == (v == 0));
            if (sel) {
                const float* gr = gi + (size_t)(st * DD + dg) * 3072 + p * 1536 + v * 768;
                const float* ghd = gh + d * GHP2;
                f32x4 hn0, hn1;
#pragma unroll
                for (int half = 0; half < 2; ++half) {
                    const int jj = j0 + half * 4;
                    f32x4 grr = *(const f32x4*)(gr + jj);
                    f32x4 grz = *(const f32x4*)(gr + HH + jj);
                    f32x4 grn = *(const f32x4*)(gr + 2 * HH + jj);
                    f32x4 ghr = *(const f32x4*)(ghd + jj);
                    f32x4 ghz = *(const f32x4*)(ghd + HH + jj);
                    f32x4 ghn = *(const f32x4*)(ghd + 2 * HH + jj);
                    f32x4 bir = *(const f32x4*)(bih + jj);
                    f32x4 biz = *(const f32x4*)(bih + HH + jj);
                    f32x4 bin = *(const f32x4*)(bih + 2 * HH + jj);
                    f32x4 bhr = *(const f32x4*)(bhh + jj);
                    f32x4 bhz = *(const f32x4*)(bhh + HH + jj);
                    f32x4 bhn = *(const f32x4*)(bhh + 2 * HH + jj);
                    f32x4 ho  = *(const f32x4*)(hof + d * HH + jj);
                    f32x4 hn_;
#pragma unroll
                    for (int m = 0; m < 4; ++m) {
                        float rg = 1.f / (1.f + __expf(-(grr[m] + bir[m] + ghr[m] + bhr[m])));
                        float zg = 1.f / (1.f + __expf(-(grz[m] + biz[m] + ghz[m] + bhz[m])));
                        float nn = tanhf(grn[m] + bin[m] + rg * (ghn[m] + bhn[m]));
                        hn_[m] = (1.f - zg) * nn + zg * ho[m];
                    }
                    if (half == 0) hn0 = hn_; else hn1 = hn_;
                }
                *(f32x4*)(hof + d * HH + j0)     = hn0;
                *(f32x4*)(hof + d * HH + j0 + 4) = hn1;
                f16x8 pk;
#pragma unroll
                for (int m = 0; m < 4; ++m) { pk[m] = (_Float16)hn0[m]; pk[4 + m] = (_Float16)hn1[m]; }
                *(f16x8*)&hpk[hchunk * 8] = pk;
                // exchange write (device-coherent)
                float* xp = xh + ((size_t)(gs & 1) * 8 + g) * 4096 + d * HH + j0;
#pragma unroll
                for (int m = 0; m < 4; ++m) {
                    __hip_atomic_store(xp + m,     hn0[m], __ATOMIC_RELAXED, __HIP_MEMORY_SCOPE_AGENT);
                    __hip_atomic_store(xp + 4 + m, hn1[m], __ATOMIC_RELAXED, __HIP_MEMORY_SCOPE_AGENT);
                }
                if (p) {
                    bf16x8 ub;
#pragma unroll
                    for (int m = 0; m < 4; ++m) {
                        ub[m]     = (short)f2bf(hn0[m]);
                        ub[4 + m] = (short)f2bf(hn1[m]);
                    }
                    size_t ch = ((size_t)(st * 8 + g) * 8 + (j0 >> 5)) * 64
                              + ((j0 >> 3) & 3) * 16 + d;
                    *(bf16x8*)((unsigned short*)outs_pk + ch * 8) = ub;
                }
            }
            __syncthreads();

            // ---- pair handshake ----
            if (tid == 0) {
                __hip_atomic_store(&flags[gs * 16 + g * 2 + v], 1,
                                   __ATOMIC_RELEASE, __HIP_MEMORY_SCOPE_AGENT);
                while (__hip_atomic_load(&flags[gs * 16 + g * 2 + (v ^ 1)],
                                         __ATOMIC_ACQUIRE, __HIP_MEMORY_SCOPE_AGENT) == 0)
                    __builtin_amdgcn_s_sleep(2);
            }
            __syncthreads();

            // ---- pull partner rows ----
            if (!sel) {
                const float* xp = xh + ((size_t)(gs & 1) * 8 + g) * 4096 + d * HH + j0;
                float hv[8];
#pragma unroll
                for (int m = 0; m < 8; ++m)
                    hv[m] = __hip_atomic_load(xp + m, __ATOMIC_RELAXED, __HIP_MEMORY_SCOPE_AGENT);
#pragma unroll
                for (int m = 0; m < 8; ++m) hof[d * HH + j0 + m] = hv[m];
                f16x8 pk;
#pragma unroll
                for (int m = 0; m < 8; ++m) pk[m] = (_Float16)hv[m];
                *(f16x8*)&hpk[hchunk * 8] = pk;
            }
            __syncthreads();
            ++gs;
        }

        if (p == 0) {
            // ---- latent (redundant in both blocks; v==0 writes outputs) ----
            const int zi0 = jq * 8;
            {
                f32x4 sm0 = {0,0,0,0}, sm1 = {0,0,0,0}, sl0 = {0,0,0,0}, sl1 = {0,0,0,0};
#pragma unroll 4
                for (int k = 0; k < HH; ++k) {
                    float hv = hof[d * HH + k];
                    const f32x4* wm = (const f32x4*)(WmT + (size_t)k * 256 + zi0);
                    const f32x4* wl = (const f32x4*)(WlT + (size_t)k * 256 + zi0);
                    sm0 += hv * wm[0]; sm1 += hv * wm[1];
                    sl0 += hv * wl[0]; sl1 += hv * wl[1];
                }
                f32x4 mean0 = sm0 + *(const f32x4*)(b_mean + zi0);
                f32x4 mean1 = sm1 + *(const f32x4*)(b_mean + zi0 + 4);
                f32x4 logv0 = sl0 + *(const f32x4*)(b_logv + zi0);
                f32x4 logv1 = sl1 + *(const f32x4*)(b_logv + zi0 + 4);
                *(f32x4*)(gh + d * GHP2 + zi0)           = mean0;
                *(f32x4*)(gh + d * GHP2 + zi0 + 4)       = mean1;
                *(f32x4*)(gh + d * GHP2 + 256 + zi0)     = logv0;
                *(f32x4*)(gh + d * GHP2 + 256 + zi0 + 4) = logv1;
                if (v == 0) {
                    *(f32x4*)(out_mean + (size_t)dg * ZZ + zi0)     = mean0;
                    *(f32x4*)(out_mean + (size_t)dg * ZZ + zi0 + 4) = mean1;
                    *(f32x4*)(out_logv + (size_t)dg * ZZ + zi0)     = logv0;
                    *(f32x4*)(out_logv + (size_t)dg * ZZ + zi0 + 4) = logv1;
                }
            }
            __syncthreads();
            {
                f32x4 zv0, zv1;
#pragma unroll
                for (int half = 0; half < 2; ++half) {
                    f32x4 mean = *(const f32x4*)(gh + d * GHP2 + zi0 + half * 4);
                    f32x4 logv = *(const f32x4*)(gh + d * GHP2 + 256 + zi0 + half * 4);
                    f32x4 ep   = *(const f32x4*)(eps + (size_t)dg * ZZ + zi0 + half * 4);
                    f32x4 zv;
#pragma unroll
                    for (int m = 0; m < 4; ++m)
                        zv[m] = ep[m] * __expf(0.5f * logv[m]) + mean[m];
                    if (half == 0) zv0 = zv; else zv1 = zv;
                }
                *(f32x4*)(gh + d * GHP2 + 512 + zi0)     = zv0;
                *(f32x4*)(gh + d * GHP2 + 512 + zi0 + 4) = zv1;
                if (v == 0) {
                    *(f32x4*)(out_z + (size_t)dg * ZZ + zi0)     = zv0;
                    *(f32x4*)(out_z + (size_t)dg * ZZ + zi0 + 4) = zv1;
                }
            }
            __syncthreads();
            {
                f32x4 s0 = {0,0,0,0}, s1 = {0,0,0,0};
#pragma unroll 4
                for (int k = 0; k < ZZ; ++k) {
                    float zv = gh[d * GHP2 + 512 + k];
                    const f32x4* wh = (const f32x4*)(WhT + (size_t)k * 256 + j0);
                    s0 += zv * wh[0]; s1 += zv * wh[1];
                }
                f32x4 h0v = s0 + *(const f32x4*)(b_l2h + j0);
                f32x4 h1v = s1 + *(const f32x4*)(b_l2h + j0 + 4);
                *(f32x4*)(hof + d * HH + j0)     = h0v;
                *(f32x4*)(hof + d * HH + j0 + 4) = h1v;
                f16x8 pk;
#pragma unroll
                for (int m = 0; m < 4; ++m) { pk[m] = (_Float16)h0v[m]; pk[4 + m] = (_Float16)h1v[m]; }
                *(f16x8*)&hpk[hchunk * 8] = pk;
            }
            __syncthreads();
        }
    }
}

// ---------------- per-row logsumexp merge (one wave per row, nt <= 64) ----------------
__global__ __launch_bounds__(64) void lse_reduce(
    const float* __restrict__ pm, const float* __restrict__ ps,
    float* __restrict__ lse, int nt)
{
    int row = blockIdx.x;
    int l = threadIdx.x;
    float m = (l < nt) ? pm[(size_t)row * nt + l] : -3.0e38f;
    float s = (l < nt) ? ps[(size_t)row * nt + l] : 0.f;
    for (int mk = 1; mk <= 32; mk <<= 1) {
        float m2 = __shfl_xor(m, mk);
        float s2 = __shfl_xor(s, mk);
        float mn = fmaxf(m, m2);
        s = s * __expf(m - mn) + s2 * __expf(m2 - mn);
        m = mn;
    }
    if (l == 0) lse[row] = m + logf(s);
}

extern "C" void kernel_launch(void* const* d_in, const int* in_sizes, int n_in,
                              void* d_out, int out_size, void* d_ws, size_t ws_size,
                              hipStream_t stream)
{
    const int*           nodes     = (const int*)d_in[0];
    const unsigned char* edges_raw = (const unsigned char*)d_in[1];
    const float* emb    = (const float*)d_in[2];
    const float* ecWih  = (const float*)d_in[3];
    const float* ecWhh  = (const float*)d_in[4];
    const float* ecbih  = (const float*)d_in[5];
    const float* ecbhh  = (const float*)d_in[6];
    const float* esWih  = (const float*)d_in[7];
    const float* esWhh  = (const float*)d_in[8];
    const float* esbih  = (const float*)d_in[9];
    const float* esbhh  = (const float*)d_in[10];
    const float* dcWih  = (const float*)d_in[11];
    const float* dcWhh  = (const float*)d_in[12];
    const float* dcbih  = (const float*)d_in[13];
    const float* dcbhh  = (const float*)d_in[14];
    const float* dsWih  = (const float*)d_in[15];
    const float* dsWhh  = (const float*)d_in[16];
    const float* dsbih  = (const float*)d_in[17];
    const float* dsbhh  = (const float*)d_in[18];
    const float* W_mean = (const float*)d_in[19];
    const float* b_mean = (const float*)d_in[20];
    const float* W_logv = (const float*)d_in[21];
    const float* b_logv = (const float*)d_in[22];
    const float* W_l2h  = (const float*)d_in[23];
    const float* b_l2h  = (const float*)d_in[24];
    const float* W_out  = (const float*)d_in[25];
    const float* b_out  = (const float*)d_in[26];
    const float* enc_init = (const float*)d_in[27];
    const float* eps    = (const float*)d_in[28];

    float* out      = (float*)d_out;
    float* out_mean = out + (size_t)TT * DD * VV;
    float* out_logv = out_mean + DD * ZZ;
    float* out_z    = out_logv + DD * ZZ;
    float* gi       = out;                  // scratch in logits region: [4096][3072]

    char* ws = (char*)d_ws;
    __hip_bfloat16* outs_pk = (__hip_bfloat16*)(ws + 0);         // 2MB
    __hip_bfloat16* Ap      = (__hip_bfloat16*)(ws + 2097152);   // 2MB
    __hip_bfloat16* Wp      = (__hip_bfloat16*)(ws + 4194304);   // 16.4MB
    __hip_bfloat16* Bp_all  = (__hip_bfloat16*)(ws + 20971520);  // 1.5MB
    _Float16*       Wf      = (_Float16*)(ws + 22544384);        // 1.5MB
    float*          WmT     = (float*)(ws + 24117248);           // 256KB
    float*          WlT     = (float*)(ws + 24379392);           // 256KB
    float*          WhT     = (float*)(ws + 24641536);           // 256KB
    float*          pm      = (float*)(ws + 24903680);           // 800KB
    float*          ps      = (float*)(ws + 25722880);           // 800KB
    float*          lse     = (float*)(ws + 26542080);           // 16KB
    unsigned char*  ecan    = (unsigned char*)(ws + 26558464);   // 4KB
    float*          xh      = (float*)(ws + 26562560);           // 256KB
    int*            flags   = (int*)(ws + 26824704);             // 4KB

    hipMemsetAsync(flags, 0, 64 * 8 * 2 * sizeof(int), stream);

    edge_canon_k<<<1, 256, 0, stream>>>(edges_raw, ecan);
    pack_frag<<<4000, 256, 0, stream>>>(W_out, Wp, 2000 * 8 * 64);
    pack_frag<<<96, 256, 0, stream>>>(ecWih, Bp_all + 0 * (size_t)48 * 4096, 48 * 8 * 64);
    pack_frag<<<96, 256, 0, stream>>>(esWih, Bp_all + 1 * (size_t)48 * 4096, 48 * 8 * 64);
    pack_frag<<<96, 256, 0, stream>>>(dcWih, Bp_all + 2 * (size_t)48 * 4096, 48 * 8 * 64);
    pack_frag<<<96, 256, 0, stream>>>(dsWih, Bp_all + 3 * (size_t)48 * 4096, 48 * 8 * 64);
    // Whh fragment-linear f16 at slot (p*2+v): ec, es, dc, ds
    pack_frag16<<<96, 256, 0, stream>>>(ecWhh, Wf + 0 * (size_t)768 * 256, 48 * 8 * 64);
    pack_frag16<<<96, 256, 0, stream>>>(esWhh, Wf + 1 * (size_t)768 * 256, 48 * 8 * 64);
    pack_frag16<<<96, 256, 0, stream>>>(dcWhh, Wf + 2 * (size_t)768 * 256, 48 * 8 * 64);
    pack_frag16<<<96, 256, 0, stream>>>(dsWhh, Wf + 3 * (size_t)768 * 256, 48 * 8 * 64);
    pack_lat_t<<<256, 256, 0, stream>>>(W_mean, WmT);
    pack_lat_t<<<256, 256, 0, stream>>>(W_logv, WlT);
    pack_lat_t<<<256, 256, 0, stream>>>(W_l2h, WhT);
    gather_pack<<<512, 256, 0, stream>>>(nodes, emb, Ap);

    // gi[4096][3072] = emb-gather x [all 4 W_ih]^T  (into d_out scratch)
    gemm_rs<true, false, false, false><<<dim3(64, 6), 256, 0, stream>>>(
        Ap, Bp_all, 3072, 8, 6, nullptr, nullptr, gi, nullptr, nullptr);

    // fused recurrence: encoder -> latent -> h0 -> decoder (writes packed outs)
    rnn_fused3<<<16, 512, 0, stream>>>(
        ecan, gi, Wf,
        ecbih, ecbhh, esbih, esbhh, dcbih, dcbhh, dsbih, dsbhh,
        WmT, WlT, WhT, b_mean, b_logv, b_l2h,
        enc_init, eps, out_mean, out_logv, out_z, outs_pk, xh, flags);

    // pass A: LSE partials only (no C write)
    gemm_rs<false, true, true, false><<<dim3(64, NTL), 256, 0, stream>>>(
        outs_pk, Wp, VV, 10, NTL, b_out, nullptr, nullptr, pm, ps);
    lse_reduce<<<4096, 64, 0, stream>>>(pm, ps, lse, NTL);
    // pass B: recompute, write logp = logits - lse
    gemm_rs<true, true, false, true><<<dim3(64, NTL), 256, 0, stream>>>(
        outs_pk, Wp, VV, 10, NTL, b_out, lse, out, nullptr, nullptr);
}